// Round 9
// baseline (126.959 us; speedup 1.0000x reference)
//
#include <hip/hip_runtime.h>

// ============================================================================
// BISECTION MEASUREMENT BUILD (R9).
// Pairs of identical dispatches: (a) = cold-first, (b) = all-warm.
//   k1 x25, k1 x25   — conv + block-partials
//   kA x30, kA x30   — cross-block reduction Pbuf -> Fbuf (the cross-XCD read)
//   kB x13, kB x13   — streaming combine kbuf/qlbuf/x/F -> out
// (a)-(b) per pair = cold excess of that phase. All idempotent/deterministic;
// final state identical to the R7 3-kernel pipeline (passed, absmax 0.25).
// ============================================================================
#define BSZ 4
#define CH  64
#define CE  8      // C/8
#define HW  4096
#define PJ  1088   // per-block partials: A 512 + B 512 + S 64
#define REP_K1 25
#define REP_A  30
#define REP_B  13

__global__ __launch_bounds__(512) void k1_kernel(
    const float* __restrict__ x,
    const float* __restrict__ qlw, const float* __restrict__ qlb,
    const float* __restrict__ kw,  const float* __restrict__ kb,
    const float* __restrict__ vw,  const float* __restrict__ vb,
    const float* __restrict__ qgw, const float* __restrict__ qgb,
    float* __restrict__ kbuf, float* __restrict__ qlbuf, float* __restrict__ Pbuf)
{
    __shared__ float vT[CH][68];
    __shared__ float kT[CE][64];

    const int tid  = threadIdx.x;
    const int lane = tid & 63;
    const int g    = __builtin_amdgcn_readfirstlane(tid >> 6);  // wave 0..7
    const int b    = blockIdx.x >> 6;
    const int p0   = (blockIdx.x & 63) << 6;
    const int p    = p0 | lane;

    for (int rep = 0; rep < REP_K1; ++rep) {
        float xv[CH];
#pragma unroll
        for (int c = 0; c < CH; ++c) xv[c] = x[(((b << 6) + c) << 12) + p];

        const int o0 = g * 10;           // scalar
#pragma unroll
        for (int i = 0; i < 10; ++i) {
            const int o = o0 + i;        // scalar 0..79
            const float* wr;
            float bias;
            if (o < 8)       { wr = kw  + (o << 6);        bias = kb[o]; }
            else if (o < 16) { wr = qlw + ((o - 8) << 6);  bias = qlb[o - 8]; }
            else             { wr = vw  + ((o - 16) << 6); bias = vb[o - 16]; }
            float acc = bias;
#pragma unroll
            for (int c = 0; c < CH; ++c) acc += wr[c] * xv[c];
            if (o < 8) {
                kbuf[(((b << 3) + o) << 12) + p] = acc;
                kT[o][lane] = acc;
            } else if (o < 16) {
                qlbuf[(((b << 3) + (o - 8)) << 12) + p] = acc;
            } else {
                vT[o - 16][lane] = acc;
            }
        }
        __syncthreads();

        {
            const int e = g & 7;         // scalar
            float a = 0.f, bb = 0.f;
#pragma unroll
            for (int pp = 0; pp < 64; pp += 4) {
                const float4 vv = *reinterpret_cast<const float4*>(&vT[lane][pp]);
                const float4 kk = *reinterpret_cast<const float4*>(&kT[e][pp]);
                const float w0 = qgw[((p0 + pp + 0) << 3) + e];
                const float w1 = qgw[((p0 + pp + 1) << 3) + e];
                const float w2 = qgw[((p0 + pp + 2) << 3) + e];
                const float w3 = qgw[((p0 + pp + 3) << 3) + e];
                a  += vv.x * w0 + vv.y * w1 + vv.z * w2 + vv.w * w3;
                bb += vv.x * kk.x + vv.y * kk.y + vv.z * kk.z + vv.w * kk.w;
            }
            float* P = Pbuf + (size_t)blockIdx.x * PJ;
            P[(e << 6) + lane] = a;
            P[512 + (e << 6) + lane] = bb;
            if (g == 0) {
                float s = 0.f;
#pragma unroll
                for (int pp = 0; pp < 64; pp += 4) {
                    const float4 vv = *reinterpret_cast<const float4*>(&vT[lane][pp]);
                    s += vv.x * qgb[p0 + pp] + vv.y * qgb[p0 + pp + 1]
                       + vv.z * qgb[p0 + pp + 2] + vv.w * qgb[p0 + pp + 3];
                }
                P[1024 + lane] = s;
            }
        }
        __syncthreads();
        asm volatile("" ::: "memory");
    }
}

// kA: cross-block reduction only. 17 blocks x 256 threads, one output each.
__global__ __launch_bounds__(256) void kA_kernel(
    const float* __restrict__ Pbuf,
    const float* __restrict__ ggp, const float* __restrict__ glp,
    float* __restrict__ Fbuf)
{
    const int t = blockIdx.x * 256 + threadIdx.x;   // 0..4351
    if (t >= BSZ * PJ) return;
    const int b = t / PJ;
    const int j = t - b * PJ;
    const float scale = (j >= 512 && j < 1024) ? glp[0] : ggp[0];
    const float* Pb = Pbuf + (size_t)(b << 6) * PJ + j;

    for (int rep = 0; rep < REP_A; ++rep) {
        float acc = 0.f;
#pragma unroll
        for (int s = 0; s < 64; ++s) acc += Pb[(size_t)s * PJ];
        Fbuf[t] = scale * acc;
        asm volatile("" ::: "memory");
    }
}

// kB: streaming combine only (F via wave-uniform s_loads from global).
__global__ __launch_bounds__(512) void kB_kernel(
    const float* __restrict__ x,
    const float* __restrict__ kbuf, const float* __restrict__ qlbuf,
    const float* __restrict__ Fbuf,
    float* __restrict__ out)
{
    const int tid  = threadIdx.x;
    const int lane = tid & 63;
    const int g    = __builtin_amdgcn_readfirstlane(tid >> 6);  // 0..7
    const int b    = blockIdx.x >> 6;
    const int p    = ((blockIdx.x & 63) << 6) | lane;
    const float* Fb = Fbuf + b * PJ;     // wave-uniform base

    for (int rep = 0; rep < REP_B; ++rep) {
        const float* kgp = kbuf + ((size_t)b << 15) + ((size_t)p << 3);
        const float4 kg0 = *reinterpret_cast<const float4*>(kgp);
        const float4 kg1 = *reinterpret_cast<const float4*>(kgp + 4);
        const float kg[8] = {kg0.x, kg0.y, kg0.z, kg0.w,
                             kg1.x, kg1.y, kg1.z, kg1.w};
        float ql[CE];
#pragma unroll
        for (int e = 0; e < CE; ++e) ql[e] = qlbuf[(((b << 3) + e) << 12) + p];

        const int c0 = g << 3;   // scalar: 8 channels per wave
#pragma unroll
        for (int ci = 0; ci < 8; ++ci) {
            const int c = c0 + ci;   // scalar
            float r = Fb[1024 + c];                       // s_load
#pragma unroll
            for (int e = 0; e < CE; ++e) {
                r += kg[e] * Fb[(e << 6) + c];            // s_load operand
                r += ql[e] * Fb[512 + (e << 6) + c];      // s_load operand
            }
            const int idx = (((b << 6) + c) << 12) + p;
            out[idx] = r + x[idx];
        }
        asm volatile("" ::: "memory");
    }
}

extern "C" void kernel_launch(void* const* d_in, const int* in_sizes, int n_in,
                              void* d_out, int out_size, void* d_ws, size_t ws_size,
                              hipStream_t stream) {
    const float* x   = (const float*)d_in[0];
    const float* qlw = (const float*)d_in[1];
    const float* qlb = (const float*)d_in[2];
    const float* kw  = (const float*)d_in[3];
    const float* kb  = (const float*)d_in[4];
    const float* vw  = (const float*)d_in[5];
    const float* vb  = (const float*)d_in[6];
    const float* qgw = (const float*)d_in[7];
    const float* qgb = (const float*)d_in[8];
    const float* gg  = (const float*)d_in[9];
    const float* gl  = (const float*)d_in[10];
    float* out = (float*)d_out;

    float* ws    = (float*)d_ws;
    float* kbuf  = ws;                        // 4*8*4096 = 131072 f
    float* qlbuf = kbuf + BSZ * CE * HW;      // 131072 f
    float* Pbuf  = qlbuf + BSZ * CE * HW;     // 256*1088 = 278528 f
    float* Fbuf  = Pbuf + 256 * PJ;           // 4*1088   = 4352 f

    k1_kernel<<<256, 512, 0, stream>>>(x, qlw, qlb, kw, kb, vw, vb, qgw, qgb,
                                       kbuf, qlbuf, Pbuf);      // (a) cold
    k1_kernel<<<256, 512, 0, stream>>>(x, qlw, qlb, kw, kb, vw, vb, qgw, qgb,
                                       kbuf, qlbuf, Pbuf);      // (b) warm
    kA_kernel<<<17, 256, 0, stream>>>(Pbuf, gg, gl, Fbuf);      // (a) cold
    kA_kernel<<<17, 256, 0, stream>>>(Pbuf, gg, gl, Fbuf);      // (b) warm
    kB_kernel<<<256, 512, 0, stream>>>(x, kbuf, qlbuf, Fbuf, out);  // (a) cold
    kB_kernel<<<256, 512, 0, stream>>>(x, kbuf, qlbuf, Fbuf, out);  // (b) warm
}